// Round 1
// baseline (92.793 us; speedup 1.0000x reference)
//
#include <hip/hip_runtime.h>
#include <stdint.h>

// ANFM: B=4096 samples, F=26 fields, V=20000, E=64, P=F*(F-1)/2=325 pairs.
// k1: per-sample block: gather -> bf16 LDS -> MFMA attention (pairs@W) ->
//     softmax -> afm, lr  (ws).   k2: MLP head 64->256->128->1 (+lr+bias).
#define B_N 4096
#define F_N 26
#define V_N 20000
#define E_N 64
#define P_N 325
#define PT  21   // ceil(336/16) pair M-tiles (padded to 336 rows)

typedef __attribute__((ext_vector_type(8))) short short8;
typedef __attribute__((ext_vector_type(4))) float floatx4;

static __device__ __forceinline__ unsigned short f2bf(float x) {
    unsigned int u = __float_as_uint(x);
    u += 0x7FFFu + ((u >> 16) & 1u);          // RNE
    return (unsigned short)(u >> 16);
}
static __device__ __forceinline__ float bf2f(unsigned short h) {
    return __uint_as_float(((unsigned int)h) << 16);
}

__global__ __launch_bounds__(256, 4) void anfm_attn_kernel(
    const int* __restrict__ x_idx, const float* __restrict__ embed_w,
    const float* __restrict__ embed_b, const float* __restrict__ att_w,
    const float* __restrict__ att_b, const float* __restrict__ att_p,
    float* __restrict__ ws_afm, float* __restrict__ ws_lr)
{
    __shared__ unsigned short xwb[F_N][72];    // bf16 gathered embeds, pad 72
    __shared__ unsigned short WT[64][72];      // attention_w transposed, bf16
    __shared__ float scoresL[336];
    __shared__ unsigned short pij[336];        // (i<<8)|j per pair
    __shared__ int   sIdx[F_N];
    __shared__ float lrbuf[F_N];
    __shared__ float ab[64], ap[64];
    __shared__ float wred[4], sred[4];
    __shared__ float afm_part[4][64];

    const int tid  = threadIdx.x;
    const int b    = blockIdx.x;
    const int lane = tid & 63;
    const int wid  = tid >> 6;
    const int c16  = lane & 15;
    const int g    = lane >> 4;

    // ---- phase 0: indices, small vectors, pair map ----
    if (tid < F_N) {
        int idx = x_idx[b * F_N + tid];
        sIdx[tid]  = idx;
        lrbuf[tid] = embed_b[tid * V_N + idx];
    }
    if (tid < 64) { ab[tid] = att_b[tid]; ap[tid] = att_p[tid]; }
    for (int p = tid; p < 336; p += 256) {
        int i = 0, j = 1;
        if (p < P_N) {
            int pi = 0, off = 0;
            while (off + (25 - pi) <= p) { off += 25 - pi; pi++; }
            i = pi; j = pi + 1 + (p - off);
        }
        pij[p] = (unsigned short)((i << 8) | j);
    }
    __syncthreads();

    // ---- phase 1: gather embeddings (f32 -> bf16 LDS), stage W^T ----
    for (int it = tid; it < F_N * 16; it += 256) {
        int f = it >> 4, q = it & 15;
        const float4* src = reinterpret_cast<const float4*>(
            embed_w + ((size_t)(f * V_N + sIdx[f])) * E_N);
        float4 v = src[q];
        ushort4 pk = make_ushort4(f2bf(v.x), f2bf(v.y), f2bf(v.z), f2bf(v.w));
        *reinterpret_cast<ushort4*>(&xwb[f][q * 4]) = pk;
    }
    for (int it = tid; it < 64 * 16; it += 256) {
        int f = it >> 4, q = it & 15;
        ushort4 pk = make_ushort4(f2bf(att_w[(q * 4 + 0) * 64 + f]),
                                  f2bf(att_w[(q * 4 + 1) * 64 + f]),
                                  f2bf(att_w[(q * 4 + 2) * 64 + f]),
                                  f2bf(att_w[(q * 4 + 3) * 64 + f]));
        *reinterpret_cast<ushort4*>(&WT[f][q * 4]) = pk;
    }
    __syncthreads();

    // ---- phase 2: attention scores via MFMA ----
    // B-frags (register-resident, reused for all M-tiles):
    // slot (g,j) <-> k = s*32 + 8g + j, consistently for A and B.
    short8 bfr[4][2];
    #pragma unroll
    for (int n = 0; n < 4; n++)
        #pragma unroll
        for (int s = 0; s < 2; s++)
            bfr[n][s] = *reinterpret_cast<const short8*>(&WT[n * 16 + c16][s * 32 + g * 8]);
    float apr[4], abr[4];
    #pragma unroll
    for (int n = 0; n < 4; n++) { apr[n] = ap[n * 16 + c16]; abr[n] = ab[n * 16 + c16]; }

    for (int t = wid; t < PT; t += 4) {
        int p  = t * 16 + c16;
        int pk = pij[p];
        int ri = pk >> 8, rj = pk & 255;
        floatx4 acc[4];
        #pragma unroll
        for (int n = 0; n < 4; n++) acc[n] = (floatx4){0.f, 0.f, 0.f, 0.f};
        #pragma unroll
        for (int s = 0; s < 2; s++) {
            short8 xv = *reinterpret_cast<const short8*>(&xwb[ri][s * 32 + g * 8]);
            short8 yv = *reinterpret_cast<const short8*>(&xwb[rj][s * 32 + g * 8]);
            short8 af;
            #pragma unroll
            for (int u = 0; u < 8; u++) {
                float prod = bf2f((unsigned short)xv[u]) * bf2f((unsigned short)yv[u]);
                af[u] = (short)f2bf(prod);
            }
            #pragma unroll
            for (int n = 0; n < 4; n++)
                acc[n] = __builtin_amdgcn_mfma_f32_16x16x32_bf16(af, bfr[n][s], acc[n], 0, 0, 0);
        }
        // D layout: col = lane&15, row = (lane>>4)*4 + reg  [guide §3, m89]
        #pragma unroll
        for (int r = 0; r < 4; r++) {
            float sc = 0.f;
            #pragma unroll
            for (int n = 0; n < 4; n++)
                sc += apr[n] * fmaxf(acc[n][r] + abr[n], 0.f);
            sc += __shfl_xor(sc, 1); sc += __shfl_xor(sc, 2);
            sc += __shfl_xor(sc, 4); sc += __shfl_xor(sc, 8);
            if (c16 == 0) scoresL[t * 16 + g * 4 + r] = sc;
        }
    }
    __syncthreads();

    // ---- phase 3: softmax over 325 scores ----
    float v1 = (tid < P_N) ? scoresL[tid] : -1e30f;
    float v2 = (tid + 256 < P_N) ? scoresL[tid + 256] : -1e30f;
    float m = fmaxf(v1, v2);
    #pragma unroll
    for (int off = 32; off; off >>= 1) m = fmaxf(m, __shfl_xor(m, off));
    if (lane == 0) wred[wid] = m;
    __syncthreads();
    float M = fmaxf(fmaxf(wred[0], wred[1]), fmaxf(wred[2], wred[3]));
    float e1 = (tid < P_N) ? __expf(v1 - M) : 0.f;
    float e2 = (tid + 256 < P_N) ? __expf(v2 - M) : 0.f;
    float sm = e1 + e2;
    #pragma unroll
    for (int off = 32; off; off >>= 1) sm += __shfl_xor(sm, off);
    if (lane == 0) sred[wid] = sm;
    if (tid < P_N) scoresL[tid] = e1;
    if (tid + 256 < P_N) scoresL[tid + 256] = e2;
    __syncthreads();
    float rZ = 1.f / (sred[0] + sred[1] + sred[2] + sred[3]);

    // ---- phase 4: afm = sum_p w_p * (xw_i o xw_j), 8 pairs/iter/wave ----
    const int pp = lane >> 3;   // pair-slot within chunk
    const int el = lane & 7;    // 8-element e-chunk
    float acc[8];
    #pragma unroll
    for (int u = 0; u < 8; u++) acc[u] = 0.f;
    for (int ch = wid; ch <= 40; ch += 4) {
        int p = ch * 8 + pp;
        bool valid = (p < P_N);
        int pk = pij[p < 336 ? p : 335];
        int ri = pk >> 8, rj = pk & 255;
        float wp = scoresL[p < 336 ? p : 335];
        wp = valid ? wp : 0.f;
        short8 xv = *reinterpret_cast<const short8*>(&xwb[ri][el * 8]);
        short8 yv = *reinterpret_cast<const short8*>(&xwb[rj][el * 8]);
        #pragma unroll
        for (int u = 0; u < 8; u++) {
            float prod = bf2f((unsigned short)xv[u]) * bf2f((unsigned short)yv[u]);
            acc[u] = fmaf(wp, prod, acc[u]);
        }
    }
    #pragma unroll
    for (int u = 0; u < 8; u++) {
        acc[u] += __shfl_xor(acc[u], 8);
        acc[u] += __shfl_xor(acc[u], 16);
        acc[u] += __shfl_xor(acc[u], 32);
    }
    if (pp == 0) {
        #pragma unroll
        for (int u = 0; u < 8; u++) afm_part[wid][el * 8 + u] = acc[u];
    }
    __syncthreads();
    if (tid < 64) {
        float a = (afm_part[0][tid] + afm_part[1][tid] +
                   afm_part[2][tid] + afm_part[3][tid]) * rZ;
        ws_afm[b * 64 + tid] = a;
    }
    if (tid == 0) {
        float lr = 0.f;
        #pragma unroll
        for (int f = 0; f < F_N; f++) lr += lrbuf[f];
        ws_lr[b] = lr;
    }
}

__global__ __launch_bounds__(256, 4) void anfm_mlp_kernel(
    const float* __restrict__ ws_afm, const float* __restrict__ ws_lr,
    const float* __restrict__ w0, const float* __restrict__ b0,
    const float* __restrict__ w1, const float* __restrict__ b1,
    const float* __restrict__ w2, const float* __restrict__ b2,
    const float* __restrict__ bias, float* __restrict__ out)
{
    __shared__ float afm_t[16][64];
    __shared__ float h0t[16][256];
    const int tid  = threadIdx.x;
    const int lane = tid & 63;
    const int w    = tid >> 6;
    const int blk  = blockIdx.x;
    const int s0   = w * 4;    // this wave's first local sample

    for (int it = tid; it < 16 * 64; it += 256) {
        int s = it >> 6, e = it & 63;
        afm_t[s][e] = ws_afm[((size_t)blk * 16 + s) * 64 + e];
    }
    __syncthreads();

    // L0: 64 -> 256
    float acc0[4][4];
    float bb0[4];
    #pragma unroll
    for (int q = 0; q < 4; q++) bb0[q] = b0[lane + 64 * q];
    #pragma unroll
    for (int s = 0; s < 4; s++)
        #pragma unroll
        for (int q = 0; q < 4; q++) acc0[s][q] = bb0[q];
    for (int e = 0; e < 64; e += 4) {
        floatx4 a[4];
        #pragma unroll
        for (int s = 0; s < 4; s++)
            a[s] = *reinterpret_cast<const floatx4*>(&afm_t[s0 + s][e]);
        #pragma unroll
        for (int k = 0; k < 4; k++) {
            float wv[4];
            #pragma unroll
            for (int q = 0; q < 4; q++) wv[q] = w0[(e + k) * 256 + lane + 64 * q];
            #pragma unroll
            for (int s = 0; s < 4; s++)
                #pragma unroll
                for (int q = 0; q < 4; q++)
                    acc0[s][q] = fmaf(a[s][k], wv[q], acc0[s][q]);
        }
    }
    #pragma unroll
    for (int s = 0; s < 4; s++)
        #pragma unroll
        for (int q = 0; q < 4; q++)
            h0t[s0 + s][lane + 64 * q] = fmaxf(acc0[s][q], 0.f);
    __syncthreads();

    // L1: 256 -> 128
    float acc1[4][2];
    float bb1[2];
    #pragma unroll
    for (int q = 0; q < 2; q++) bb1[q] = b1[lane + 64 * q];
    #pragma unroll
    for (int s = 0; s < 4; s++)
        #pragma unroll
        for (int q = 0; q < 2; q++) acc1[s][q] = bb1[q];
    for (int e = 0; e < 256; e += 4) {
        floatx4 h[4];
        #pragma unroll
        for (int s = 0; s < 4; s++)
            h[s] = *reinterpret_cast<const floatx4*>(&h0t[s0 + s][e]);
        #pragma unroll
        for (int k = 0; k < 4; k++) {
            float wv[2];
            #pragma unroll
            for (int q = 0; q < 2; q++) wv[q] = w1[(e + k) * 128 + lane + 64 * q];
            #pragma unroll
            for (int s = 0; s < 4; s++)
                #pragma unroll
                for (int q = 0; q < 2; q++)
                    acc1[s][q] = fmaf(h[s][k], wv[q], acc1[s][q]);
        }
    }

    // L2: 128 -> 1, + lr + bias
    float w2a = w2[lane], w2b = w2[lane + 64];
    float base = b2[0] + bias[0];
    #pragma unroll
    for (int s = 0; s < 4; s++) {
        float part = fmaxf(acc1[s][0], 0.f) * w2a + fmaxf(acc1[s][1], 0.f) * w2b;
        #pragma unroll
        for (int off = 32; off; off >>= 1) part += __shfl_xor(part, off);
        if (lane == 0) {
            int sg = blk * 16 + s0 + s;
            out[sg] = part + base + ws_lr[sg];
        }
    }
}

extern "C" void kernel_launch(void* const* d_in, const int* in_sizes, int n_in,
                              void* d_out, int out_size, void* d_ws, size_t ws_size,
                              hipStream_t stream) {
    const int*   x_idx   = (const int*)d_in[0];
    const float* embed_w = (const float*)d_in[1];
    const float* embed_b = (const float*)d_in[2];
    const float* att_w   = (const float*)d_in[3];
    const float* att_b   = (const float*)d_in[4];
    const float* att_p   = (const float*)d_in[5];
    const float* w0      = (const float*)d_in[6];
    const float* b0      = (const float*)d_in[7];
    const float* w1      = (const float*)d_in[8];
    const float* b1      = (const float*)d_in[9];
    const float* w2      = (const float*)d_in[10];
    const float* b2      = (const float*)d_in[11];
    const float* bias    = (const float*)d_in[12];

    float* ws_afm = (float*)d_ws;                    // [B, 64] f32
    float* ws_lr  = ws_afm + (size_t)B_N * E_N;      // [B] f32
    float* out    = (float*)d_out;

    anfm_attn_kernel<<<B_N, 256, 0, stream>>>(x_idx, embed_w, embed_b,
                                              att_w, att_b, att_p, ws_afm, ws_lr);
    anfm_mlp_kernel<<<B_N / 16, 256, 0, stream>>>(ws_afm, ws_lr,
                                                  w0, b0, w1, b1, w2, b2, bias, out);
}

// Round 2
// 89.601 us; speedup vs baseline: 1.0356x; 1.0356x over previous
//
#include <hip/hip_runtime.h>
#include <stdint.h>

// ANFM: B=4096, F=26, V=20000, E=64, P=325 pairs.
// k0 (pre): pair map + W^T fp16 -> ws.
// k1: per-sample block: gather->fp16 LDS -> MFMA attention -> softmax -> afm,lr.
// k2: MLP head 64->256->128->1 (+lr+bias).
#define B_N 4096
#define F_N 26
#define V_N 20000
#define E_N 64
#define P_N 325
#define PT  21   // ceil(336/16) pair M-tiles (padded to 336 rows)

typedef __attribute__((ext_vector_type(8))) _Float16 half8;
typedef __attribute__((ext_vector_type(4))) _Float16 half4;
typedef __attribute__((ext_vector_type(4))) float floatx4;

// ---------------- pre-kernel: pair map + transposed fp16 W ----------------
__global__ void anfm_pre_kernel(const float* __restrict__ att_w,
                                unsigned short* __restrict__ ws_pij,
                                _Float16* __restrict__ ws_wt)
{
    const int tid = threadIdx.x;
    for (int p = tid; p < 336; p += 256) {
        int i = 0, j = 1;
        if (p < P_N) {
            int pi = 0, off = 0;
            while (off + (25 - pi) <= p) { off += 25 - pi; pi++; }
            i = pi; j = pi + 1 + (p - off);
        }
        ws_pij[p] = (unsigned short)((i << 8) | j);
    }
    // ws_wt[col][k] = att_w[k][col]  (fp16)
    for (int idx = tid; idx < 64 * 64; idx += 256) {
        int col = idx >> 6, k = idx & 63;
        ws_wt[col * 64 + k] = (_Float16)att_w[k * 64 + col];
    }
}

// ---------------- attention kernel: one sample per block ----------------
__global__ __launch_bounds__(256, 8) void anfm_attn_kernel(
    const int* __restrict__ x_idx, const float* __restrict__ embed_w,
    const float* __restrict__ embed_b, const float* __restrict__ att_b,
    const float* __restrict__ att_p, const unsigned short* __restrict__ ws_pij,
    const _Float16* __restrict__ ws_wt,
    float* __restrict__ ws_afm, float* __restrict__ ws_lr)
{
    __shared__ _Float16 xwb[F_N][72];          // fp16 gathered embeds (pad 72)
    __shared__ float scoresL[336];
    __shared__ unsigned short pijL[336];       // (i<<8)|j per pair
    __shared__ int   sIdx[F_N];
    __shared__ float lrbuf[F_N];
    __shared__ float wred[4], sred[4];
    __shared__ float afm_part[4][64];

    const int tid  = threadIdx.x;
    const int b    = blockIdx.x;
    const int lane = tid & 63;
    const int wid  = tid >> 6;
    const int c16  = lane & 15;
    const int g    = lane >> 4;

    // ---- phase 0: indices, lr gather, pair map load ----
    if (tid < F_N) {
        int idx = x_idx[b * F_N + tid];
        sIdx[tid]  = idx;
        lrbuf[tid] = embed_b[tid * V_N + idx];
    }
    for (int p = tid; p < 336; p += 256) pijL[p] = ws_pij[p];
    __syncthreads();

    // ---- phase 1: gather embeddings (f32 -> fp16 LDS) ----
    for (int it = tid; it < F_N * 16; it += 256) {
        int f = it >> 4, q = it & 15;
        const float4* src = reinterpret_cast<const float4*>(
            embed_w + ((size_t)(f * V_N + sIdx[f])) * E_N);
        float4 v = src[q];
        half4 hv = {(_Float16)v.x, (_Float16)v.y, (_Float16)v.z, (_Float16)v.w};
        *reinterpret_cast<half4*>(&xwb[f][q * 4]) = hv;
    }

    // B-frags from precomputed W^T (register-resident, reused all M-tiles).
    // slot (g,u) <-> k = s*32 + 8g + u, consistently for A and B.
    half8 bfr[4][2];
    #pragma unroll
    for (int n = 0; n < 4; n++)
        #pragma unroll
        for (int s = 0; s < 2; s++)
            bfr[n][s] = *reinterpret_cast<const half8*>(
                &ws_wt[(n * 16 + c16) * 64 + s * 32 + g * 8]);
    float apr[4], abr[4];
    #pragma unroll
    for (int n = 0; n < 4; n++) {
        apr[n] = att_p[n * 16 + c16];
        abr[n] = att_b[n * 16 + c16];
    }
    __syncthreads();

    // ---- phase 2: attention scores via MFMA ----
    for (int t = wid; t < PT; t += 4) {
        int p  = t * 16 + c16;
        int pk = pijL[p];
        int ri = pk >> 8, rj = pk & 255;
        floatx4 acc[4];
        #pragma unroll
        for (int n = 0; n < 4; n++) acc[n] = (floatx4){0.f, 0.f, 0.f, 0.f};
        #pragma unroll
        for (int s = 0; s < 2; s++) {
            half8 xv = *reinterpret_cast<const half8*>(&xwb[ri][s * 32 + g * 8]);
            half8 yv = *reinterpret_cast<const half8*>(&xwb[rj][s * 32 + g * 8]);
            half8 af = xv * yv;   // 4x v_pk_mul_f16
            #pragma unroll
            for (int n = 0; n < 4; n++)
                acc[n] = __builtin_amdgcn_mfma_f32_16x16x32_f16(af, bfr[n][s], acc[n], 0, 0, 0);
        }
        // D layout: col = lane&15, row = (lane>>4)*4 + reg
        #pragma unroll
        for (int r = 0; r < 4; r++) {
            float sc = 0.f;
            #pragma unroll
            for (int n = 0; n < 4; n++)
                sc += apr[n] * fmaxf(acc[n][r] + abr[n], 0.f);
            sc += __shfl_xor(sc, 1); sc += __shfl_xor(sc, 2);
            sc += __shfl_xor(sc, 4); sc += __shfl_xor(sc, 8);
            if (c16 == 0) scoresL[t * 16 + g * 4 + r] = sc;
        }
    }
    __syncthreads();

    // ---- phase 3: softmax over 325 scores ----
    float v1 = (tid < P_N) ? scoresL[tid] : -1e30f;
    float v2 = (tid + 256 < P_N) ? scoresL[tid + 256] : -1e30f;
    float m = fmaxf(v1, v2);
    #pragma unroll
    for (int off = 32; off; off >>= 1) m = fmaxf(m, __shfl_xor(m, off));
    if (lane == 0) wred[wid] = m;
    __syncthreads();
    float M = fmaxf(fmaxf(wred[0], wred[1]), fmaxf(wred[2], wred[3]));
    float e1 = (tid < P_N) ? __expf(v1 - M) : 0.f;
    float e2 = (tid + 256 < P_N) ? __expf(v2 - M) : 0.f;
    float sm = e1 + e2;
    #pragma unroll
    for (int off = 32; off; off >>= 1) sm += __shfl_xor(sm, off);
    if (lane == 0) sred[wid] = sm;
    if (tid < P_N) scoresL[tid] = e1;
    if (tid + 256 < P_N) scoresL[tid + 256] = e2;
    __syncthreads();
    float rZ = 1.f / (sred[0] + sred[1] + sred[2] + sred[3]);

    // ---- phase 4: afm = sum_p w_p * (xw_i o xw_j), 8 pairs/iter/wave ----
    const int pp = lane >> 3;   // pair-slot within chunk
    const int el = lane & 7;    // 8-element e-chunk
    float acc[8];
    #pragma unroll
    for (int u = 0; u < 8; u++) acc[u] = 0.f;
    for (int ch = wid; ch <= 40; ch += 4) {
        int p = ch * 8 + pp;
        bool valid = (p < P_N);
        int pc = p < 336 ? p : 335;
        int pk = pijL[pc];
        int ri = pk >> 8, rj = pk & 255;
        float wp = valid ? scoresL[pc] : 0.f;
        half8 xv = *reinterpret_cast<const half8*>(&xwb[ri][el * 8]);
        half8 yv = *reinterpret_cast<const half8*>(&xwb[rj][el * 8]);
        half8 pr = xv * yv;
        #pragma unroll
        for (int u = 0; u < 8; u++)
            acc[u] = fmaf(wp, (float)pr[u], acc[u]);
    }
    #pragma unroll
    for (int u = 0; u < 8; u++) {
        acc[u] += __shfl_xor(acc[u], 8);
        acc[u] += __shfl_xor(acc[u], 16);
        acc[u] += __shfl_xor(acc[u], 32);
    }
    if (pp == 0) {
        #pragma unroll
        for (int u = 0; u < 8; u++) afm_part[wid][el * 8 + u] = acc[u];
    }
    __syncthreads();
    if (tid < 64) {
        float a = (afm_part[0][tid] + afm_part[1][tid] +
                   afm_part[2][tid] + afm_part[3][tid]) * rZ;
        ws_afm[b * 64 + tid] = a;
    }
    if (tid == 0) {
        float lr = 0.f;
        #pragma unroll
        for (int f = 0; f < F_N; f++) lr += lrbuf[f];
        ws_lr[b] = lr;
    }
}

// ---------------- MLP head: 16 samples per block ----------------
__global__ __launch_bounds__(256, 4) void anfm_mlp_kernel(
    const float* __restrict__ ws_afm, const float* __restrict__ ws_lr,
    const float* __restrict__ w0, const float* __restrict__ b0,
    const float* __restrict__ w1, const float* __restrict__ b1,
    const float* __restrict__ w2, const float* __restrict__ b2,
    const float* __restrict__ bias, float* __restrict__ out)
{
    __shared__ float afm_t[16][64];
    __shared__ float h0t[16][256];
    const int tid  = threadIdx.x;
    const int lane = tid & 63;
    const int w    = tid >> 6;
    const int blk  = blockIdx.x;
    const int s0   = w * 4;    // this wave's first local sample

    for (int it = tid; it < 16 * 64; it += 256) {
        int s = it >> 6, e = it & 63;
        afm_t[s][e] = ws_afm[((size_t)blk * 16 + s) * 64 + e];
    }
    __syncthreads();

    // L0: 64 -> 256
    float acc0[4][4];
    float bb0[4];
    #pragma unroll
    for (int q = 0; q < 4; q++) bb0[q] = b0[lane + 64 * q];
    #pragma unroll
    for (int s = 0; s < 4; s++)
        #pragma unroll
        for (int q = 0; q < 4; q++) acc0[s][q] = bb0[q];
    for (int e = 0; e < 64; e += 4) {
        floatx4 a[4];
        #pragma unroll
        for (int s = 0; s < 4; s++)
            a[s] = *reinterpret_cast<const floatx4*>(&afm_t[s0 + s][e]);
        #pragma unroll
        for (int k = 0; k < 4; k++) {
            float wv[4];
            #pragma unroll
            for (int q = 0; q < 4; q++) wv[q] = w0[(e + k) * 256 + lane + 64 * q];
            #pragma unroll
            for (int s = 0; s < 4; s++)
                #pragma unroll
                for (int q = 0; q < 4; q++)
                    acc0[s][q] = fmaf(a[s][k], wv[q], acc0[s][q]);
        }
    }
    #pragma unroll
    for (int s = 0; s < 4; s++)
        #pragma unroll
        for (int q = 0; q < 4; q++)
            h0t[s0 + s][lane + 64 * q] = fmaxf(acc0[s][q], 0.f);
    __syncthreads();

    // L1: 256 -> 128
    float acc1[4][2];
    float bb1[2];
    #pragma unroll
    for (int q = 0; q < 2; q++) bb1[q] = b1[lane + 64 * q];
    #pragma unroll
    for (int s = 0; s < 4; s++)
        #pragma unroll
        for (int q = 0; q < 2; q++) acc1[s][q] = bb1[q];
    for (int e = 0; e < 256; e += 4) {
        floatx4 h[4];
        #pragma unroll
        for (int s = 0; s < 4; s++)
            h[s] = *reinterpret_cast<const floatx4*>(&h0t[s0 + s][e]);
        #pragma unroll
        for (int k = 0; k < 4; k++) {
            float wv[2];
            #pragma unroll
            for (int q = 0; q < 2; q++) wv[q] = w1[(e + k) * 128 + lane + 64 * q];
            #pragma unroll
            for (int s = 0; s < 4; s++)
                #pragma unroll
                for (int q = 0; q < 2; q++)
                    acc1[s][q] = fmaf(h[s][k], wv[q], acc1[s][q]);
        }
    }

    // L2: 128 -> 1, + lr + bias
    float w2a = w2[lane], w2b = w2[lane + 64];
    float base = b2[0] + bias[0];
    #pragma unroll
    for (int s = 0; s < 4; s++) {
        float part = fmaxf(acc1[s][0], 0.f) * w2a + fmaxf(acc1[s][1], 0.f) * w2b;
        #pragma unroll
        for (int off = 32; off; off >>= 1) part += __shfl_xor(part, off);
        if (lane == 0) {
            int sg = blk * 16 + s0 + s;
            out[sg] = part + base + ws_lr[sg];
        }
    }
}

extern "C" void kernel_launch(void* const* d_in, const int* in_sizes, int n_in,
                              void* d_out, int out_size, void* d_ws, size_t ws_size,
                              hipStream_t stream) {
    const int*   x_idx   = (const int*)d_in[0];
    const float* embed_w = (const float*)d_in[1];
    const float* embed_b = (const float*)d_in[2];
    const float* att_w   = (const float*)d_in[3];
    const float* att_b   = (const float*)d_in[4];
    const float* att_p   = (const float*)d_in[5];
    const float* w0      = (const float*)d_in[6];
    const float* b0      = (const float*)d_in[7];
    const float* w1      = (const float*)d_in[8];
    const float* b1      = (const float*)d_in[9];
    const float* w2      = (const float*)d_in[10];
    const float* b2      = (const float*)d_in[11];
    const float* bias    = (const float*)d_in[12];

    // ws layout: afm [B,64] f32 | lr [B] f32 | pij [336+pad] u16 | wt [64*64] f16
    float*          ws_afm = (float*)d_ws;
    float*          ws_lr  = ws_afm + (size_t)B_N * E_N;
    unsigned short* ws_pij = (unsigned short*)(ws_lr + B_N);
    _Float16*       ws_wt  = (_Float16*)((char*)ws_pij + 1024);
    float*          out    = (float*)d_out;

    anfm_pre_kernel<<<1, 256, 0, stream>>>(att_w, ws_pij, ws_wt);
    anfm_attn_kernel<<<B_N, 256, 0, stream>>>(x_idx, embed_w, embed_b,
                                              att_b, att_p, ws_pij, ws_wt,
                                              ws_afm, ws_lr);
    anfm_mlp_kernel<<<B_N / 16, 256, 0, stream>>>(ws_afm, ws_lr,
                                                  w0, b0, w1, b1, w2, b2, bias, out);
}

// Round 3
// 71.100 us; speedup vs baseline: 1.3051x; 1.2602x over previous
//
#include <hip/hip_runtime.h>
#include <stdint.h>

// ANFM: B=4096, F=26, V=20000, E=64, P=325 pairs.
// k1: per-sample block: gather->fp16 LDS -> MFMA attention -> softmax -> afm,lr.
//     W^T staged in LDS (no persistent reg fragments -> no spill at high occ).
// k2: MLP head 64->256->128->1 (+lr+bias), 16 samples/block.
#define B_N 4096
#define F_N 26
#define V_N 20000
#define E_N 64
#define P_N 325
#define PT  21   // ceil(336/16) pair M-tiles (padded to 336 rows)

typedef __attribute__((ext_vector_type(8))) _Float16 half8;
typedef __attribute__((ext_vector_type(4))) _Float16 half4;
typedef __attribute__((ext_vector_type(4))) float floatx4;

// ---------------- attention kernel: one sample per block ----------------
__global__ __launch_bounds__(256, 6) void anfm_attn_kernel(
    const int* __restrict__ x_idx, const float* __restrict__ embed_w,
    const float* __restrict__ embed_b, const float* __restrict__ att_w,
    const float* __restrict__ att_b, const float* __restrict__ att_p,
    float* __restrict__ ws_afm, float* __restrict__ ws_lr)
{
    __shared__ _Float16 xwb[F_N][72];          // fp16 gathered embeds (pad 72)
    __shared__ _Float16 WT[64][72];            // W^T fp16: WT[col][k] (pad 72)
    __shared__ float scoresL[336];
    __shared__ unsigned short pijL[336];       // (i<<8)|j per pair
    __shared__ int   sIdx[F_N];
    __shared__ float lrbuf[F_N];
    __shared__ float apL[64], abL[64];
    __shared__ float wred[4], sred[4];
    __shared__ float afm_part[4][64];

    const int tid  = threadIdx.x;
    const int b    = blockIdx.x;
    const int lane = tid & 63;
    const int wid  = tid >> 6;
    const int c16  = lane & 15;
    const int g    = lane >> 4;

    // ---- phase 0: indices, lr gather, small vectors, pair map (closed form) ----
    if (tid < F_N) {
        int idx = x_idx[b * F_N + tid];
        sIdx[tid]  = idx;
        lrbuf[tid] = embed_b[tid * V_N + idx];
    }
    if (tid < 64) { apL[tid] = att_p[tid]; abL[tid] = att_b[tid]; }
    for (int p = tid; p < 336; p += 256) {
        int i = 0, j = 1;
        if (p < P_N) {
            i = (int)((51.0f - sqrtf(2601.0f - 8.0f * (float)p)) * 0.5f);
            if (i * (51 - i) / 2 > p) i--;
            else if ((i + 1) * (50 - i) / 2 <= p) i++;
            j = p - i * (51 - i) / 2 + i + 1;
        }
        pijL[p] = (unsigned short)((i << 8) | j);
    }
    // W^T staging: WT[col][k] = att_w[k][col]  (f32 coalesced read, fp16 LDS write)
    for (int idx = tid; idx < 64 * 64; idx += 256) {
        int k = idx >> 6, col = idx & 63;
        WT[col][k] = (_Float16)att_w[idx];
    }
    __syncthreads();

    // ---- phase 1: gather embeddings (f32 -> fp16 LDS) ----
    for (int it = tid; it < F_N * 16; it += 256) {
        int f = it >> 4, q = it & 15;
        const float4* src = reinterpret_cast<const float4*>(
            embed_w + ((size_t)(f * V_N + sIdx[f])) * E_N);
        float4 v = src[q];
        half4 hv = {(_Float16)v.x, (_Float16)v.y, (_Float16)v.z, (_Float16)v.w};
        *reinterpret_cast<half4*>(&xwb[f][q * 4]) = hv;
    }
    __syncthreads();

    // ---- phase 2: attention scores via MFMA ----
    // K-slot map: (g,u) <-> k = s*32 + 8g + u, same for A and B fragments.
    for (int t = wid; t < PT; t += 4) {
        int p  = t * 16 + c16;
        int pk = pijL[p];
        int ri = pk >> 8, rj = pk & 255;
        half8 af[2];
        #pragma unroll
        for (int s = 0; s < 2; s++) {
            half8 xv = *reinterpret_cast<const half8*>(&xwb[ri][s * 32 + g * 8]);
            half8 yv = *reinterpret_cast<const half8*>(&xwb[rj][s * 32 + g * 8]);
            af[s] = xv * yv;   // 4x v_pk_mul_f16
        }
        float scq[4] = {0.f, 0.f, 0.f, 0.f};
        #pragma unroll
        for (int n = 0; n < 4; n++) {
            floatx4 acc = (floatx4){0.f, 0.f, 0.f, 0.f};
            #pragma unroll
            for (int s = 0; s < 2; s++) {
                half8 bfr = *reinterpret_cast<const half8*>(
                    &WT[n * 16 + c16][s * 32 + g * 8]);
                acc = __builtin_amdgcn_mfma_f32_16x16x32_f16(af[s], bfr, acc, 0, 0, 0);
            }
            float apn = apL[n * 16 + c16];
            float abn = abL[n * 16 + c16];
            #pragma unroll
            for (int r = 0; r < 4; r++)
                scq[r] += apn * fmaxf(acc[r] + abn, 0.f);
        }
        // D layout: col = lane&15 (hidden), row = (lane>>4)*4 + reg (pair)
        #pragma unroll
        for (int r = 0; r < 4; r++) {
            float sc = scq[r];
            sc += __shfl_xor(sc, 1); sc += __shfl_xor(sc, 2);
            sc += __shfl_xor(sc, 4); sc += __shfl_xor(sc, 8);
            if (c16 == 0) scoresL[t * 16 + g * 4 + r] = sc;
        }
    }
    __syncthreads();

    // ---- phase 3: softmax over 325 scores ----
    float v1 = (tid < P_N) ? scoresL[tid] : -1e30f;
    float v2 = (tid + 256 < P_N) ? scoresL[tid + 256] : -1e30f;
    float m = fmaxf(v1, v2);
    #pragma unroll
    for (int off = 32; off; off >>= 1) m = fmaxf(m, __shfl_xor(m, off));
    if (lane == 0) wred[wid] = m;
    __syncthreads();
    float M = fmaxf(fmaxf(wred[0], wred[1]), fmaxf(wred[2], wred[3]));
    float e1 = (tid < P_N) ? __expf(v1 - M) : 0.f;
    float e2 = (tid + 256 < P_N) ? __expf(v2 - M) : 0.f;
    float sm = e1 + e2;
    #pragma unroll
    for (int off = 32; off; off >>= 1) sm += __shfl_xor(sm, off);
    if (lane == 0) sred[wid] = sm;
    if (tid < P_N) scoresL[tid] = e1;
    if (tid + 256 < P_N) scoresL[tid + 256] = e2;
    __syncthreads();
    float rZ = 1.f / (sred[0] + sred[1] + sred[2] + sred[3]);

    // ---- phase 4: afm = sum_p w_p * (xw_i o xw_j), 8 pairs/iter/wave ----
    const int pp = lane >> 3;   // pair-slot within chunk
    const int el = lane & 7;    // 8-element e-chunk
    float acc[8];
    #pragma unroll
    for (int u = 0; u < 8; u++) acc[u] = 0.f;
    for (int ch = wid; ch <= 40; ch += 4) {
        int p = ch * 8 + pp;
        bool valid = (p < P_N);
        int pc = p < 336 ? p : 335;
        int pk = pijL[pc];
        int ri = pk >> 8, rj = pk & 255;
        float wp = valid ? scoresL[pc] : 0.f;
        half8 xv = *reinterpret_cast<const half8*>(&xwb[ri][el * 8]);
        half8 yv = *reinterpret_cast<const half8*>(&xwb[rj][el * 8]);
        half8 pr = xv * yv;
        #pragma unroll
        for (int u = 0; u < 8; u++)
            acc[u] = fmaf(wp, (float)pr[u], acc[u]);
    }
    #pragma unroll
    for (int u = 0; u < 8; u++) {
        acc[u] += __shfl_xor(acc[u], 8);
        acc[u] += __shfl_xor(acc[u], 16);
        acc[u] += __shfl_xor(acc[u], 32);
    }
    if (pp == 0) {
        #pragma unroll
        for (int u = 0; u < 8; u++) afm_part[wid][el * 8 + u] = acc[u];
    }
    __syncthreads();
    if (tid < 64) {
        float a = (afm_part[0][tid] + afm_part[1][tid] +
                   afm_part[2][tid] + afm_part[3][tid]) * rZ;
        ws_afm[b * 64 + tid] = a;
    }
    if (tid == 0) {
        float lr = 0.f;
        #pragma unroll
        for (int f = 0; f < F_N; f++) lr += lrbuf[f];
        ws_lr[b] = lr;
    }
}

// ---------------- MLP head: 16 samples per block ----------------
__global__ __launch_bounds__(256, 4) void anfm_mlp_kernel(
    const float* __restrict__ ws_afm, const float* __restrict__ ws_lr,
    const float* __restrict__ w0, const float* __restrict__ b0,
    const float* __restrict__ w1, const float* __restrict__ b1,
    const float* __restrict__ w2, const float* __restrict__ b2,
    const float* __restrict__ bias, float* __restrict__ out)
{
    __shared__ float afm_t[16][64];
    __shared__ float h0t[16][256];
    const int tid  = threadIdx.x;
    const int lane = tid & 63;
    const int w    = tid >> 6;
    const int blk  = blockIdx.x;
    const int s0   = w * 4;    // this wave's first local sample

    for (int it = tid; it < 16 * 64; it += 256) {
        int s = it >> 6, e = it & 63;
        afm_t[s][e] = ws_afm[((size_t)blk * 16 + s) * 64 + e];
    }
    __syncthreads();

    // L0: 64 -> 256
    float acc0[4][4];
    float bb0[4];
    #pragma unroll
    for (int q = 0; q < 4; q++) bb0[q] = b0[lane + 64 * q];
    #pragma unroll
    for (int s = 0; s < 4; s++)
        #pragma unroll
        for (int q = 0; q < 4; q++) acc0[s][q] = bb0[q];
    for (int e = 0; e < 64; e += 4) {
        floatx4 a[4];
        #pragma unroll
        for (int s = 0; s < 4; s++)
            a[s] = *reinterpret_cast<const floatx4*>(&afm_t[s0 + s][e]);
        #pragma unroll
        for (int k = 0; k < 4; k++) {
            float wv[4];
            #pragma unroll
            for (int q = 0; q < 4; q++) wv[q] = w0[(e + k) * 256 + lane + 64 * q];
            #pragma unroll
            for (int s = 0; s < 4; s++)
                #pragma unroll
                for (int q = 0; q < 4; q++)
                    acc0[s][q] = fmaf(a[s][k], wv[q], acc0[s][q]);
        }
    }
    #pragma unroll
    for (int s = 0; s < 4; s++)
        #pragma unroll
        for (int q = 0; q < 4; q++)
            h0t[s0 + s][lane + 64 * q] = fmaxf(acc0[s][q], 0.f);
    __syncthreads();

    // L1: 256 -> 128
    float acc1[4][2];
    float bb1[2];
    #pragma unroll
    for (int q = 0; q < 2; q++) bb1[q] = b1[lane + 64 * q];
    #pragma unroll
    for (int s = 0; s < 4; s++)
        #pragma unroll
        for (int q = 0; q < 2; q++) acc1[s][q] = bb1[q];
    for (int e = 0; e < 256; e += 4) {
        floatx4 h[4];
        #pragma unroll
        for (int s = 0; s < 4; s++)
            h[s] = *reinterpret_cast<const floatx4*>(&h0t[s0 + s][e]);
        #pragma unroll
        for (int k = 0; k < 4; k++) {
            float wv[2];
            #pragma unroll
            for (int q = 0; q < 2; q++) wv[q] = w1[(e + k) * 128 + lane + 64 * q];
            #pragma unroll
            for (int s = 0; s < 4; s++)
                #pragma unroll
                for (int q = 0; q < 2; q++)
                    acc1[s][q] = fmaf(h[s][k], wv[q], acc1[s][q]);
        }
    }

    // L2: 128 -> 1, + lr + bias
    float w2a = w2[lane], w2b = w2[lane + 64];
    float base = b2[0] + bias[0];
    #pragma unroll
    for (int s = 0; s < 4; s++) {
        float part = fmaxf(acc1[s][0], 0.f) * w2a + fmaxf(acc1[s][1], 0.f) * w2b;
        #pragma unroll
        for (int off = 32; off; off >>= 1) part += __shfl_xor(part, off);
        if (lane == 0) {
            int sg = blk * 16 + s0 + s;
            out[sg] = part + base + ws_lr[sg];
        }
    }
}

extern "C" void kernel_launch(void* const* d_in, const int* in_sizes, int n_in,
                              void* d_out, int out_size, void* d_ws, size_t ws_size,
                              hipStream_t stream) {
    const int*   x_idx   = (const int*)d_in[0];
    const float* embed_w = (const float*)d_in[1];
    const float* embed_b = (const float*)d_in[2];
    const float* att_w   = (const float*)d_in[3];
    const float* att_b   = (const float*)d_in[4];
    const float* att_p   = (const float*)d_in[5];
    const float* w0      = (const float*)d_in[6];
    const float* b0      = (const float*)d_in[7];
    const float* w1      = (const float*)d_in[8];
    const float* b1      = (const float*)d_in[9];
    const float* w2      = (const float*)d_in[10];
    const float* b2      = (const float*)d_in[11];
    const float* bias    = (const float*)d_in[12];

    // ws layout: afm [B,64] f32 | lr [B] f32
    float* ws_afm = (float*)d_ws;
    float* ws_lr  = ws_afm + (size_t)B_N * E_N;
    float* out    = (float*)d_out;

    anfm_attn_kernel<<<B_N, 256, 0, stream>>>(x_idx, embed_w, embed_b,
                                              att_w, att_b, att_p,
                                              ws_afm, ws_lr);
    anfm_mlp_kernel<<<B_N / 16, 256, 0, stream>>>(ws_afm, ws_lr,
                                                  w0, b0, w1, b1, w2, b2, bias, out);
}

// Round 5
// 68.080 us; speedup vs baseline: 1.3630x; 1.0444x over previous
//
#include <hip/hip_runtime.h>
#include <stdint.h>

// ANFM: B=4096, F=26, V=20000, E=64, P=325 pairs.
// k1: 2 samples/block, one wave-pair per sample. Self-contained: pair map
//     (closed form) + W^T (LDS stage from att_w) built in-block; W-fragments
//     hoisted to registers once; MFMA attention -> softmax -> afm,lr -> ws.
// k2: MLP head 64->256->128->1 (+lr+bias), 16 samples/block.
// NOTE: no cross-kernel ws metadata (round-4 tripwire lesson); only the
// attn->mlp afm/lr handoff, which passed the tripwire in rounds 2-3.
#define B_N 4096
#define F_N 26
#define V_N 20000
#define E_N 64
#define P_N 325
#define PT  21   // ceil(336/16) pair M-tiles (padded to 336 rows)

typedef __attribute__((ext_vector_type(8))) _Float16 half8;
typedef __attribute__((ext_vector_type(4))) _Float16 half4;
typedef __attribute__((ext_vector_type(4))) float floatx4;

// ---------------- attention kernel: 2 samples per block ----------------
__global__ __launch_bounds__(256, 5) void anfm_attn_kernel(
    const int* __restrict__ x_idx, const float* __restrict__ embed_w,
    const float* __restrict__ embed_b, const float* __restrict__ att_w,
    const float* __restrict__ att_b, const float* __restrict__ att_p,
    float* __restrict__ ws_afm, float* __restrict__ ws_lr)
{
    __shared__ _Float16 xwb[2][F_N][72];   // fp16 gathered embeds (pad 72)
    __shared__ _Float16 WT[64][72];        // W^T fp16: WT[col][k] (pad 72)
    __shared__ float scoresL[2][344];
    __shared__ unsigned short pijL[336];   // (i<<8)|j per pair
    __shared__ int   sIdx[2][F_N];
    __shared__ float lrbuf[2][F_N];
    __shared__ float wred[2][2], sred[2][2];
    __shared__ float afm_part[2][2][64];

    const int tid  = threadIdx.x;
    const int b0   = blockIdx.x * 2;
    const int lane = tid & 63;
    const int wid  = tid >> 6;
    const int c16  = lane & 15;
    const int g    = lane >> 4;
    const int smp  = wid >> 1;   // sample this wave owns in phases 2-4
    const int wv   = wid & 1;    // wave index within the pair

    // ---- phase 0: indices, lr gather, pair map (closed form), W^T stage ----
    if (tid < 2 * F_N) {
        int s = (tid >= F_N) ? 1 : 0;
        int f = tid - s * F_N;
        int idx = x_idx[(b0 + s) * F_N + f];
        sIdx[s][f]  = idx;
        lrbuf[s][f] = embed_b[f * V_N + idx];
    }
    for (int p = tid; p < 336; p += 256) {
        int i = 0, j = 1;
        if (p < P_N) {
            i = (int)((51.0f - sqrtf(2601.0f - 8.0f * (float)p)) * 0.5f);
            if (i * (51 - i) / 2 > p) i--;
            else if ((i + 1) * (50 - i) / 2 <= p) i++;
            j = p - i * (51 - i) / 2 + i + 1;
        }
        pijL[p] = (unsigned short)((i << 8) | j);
    }
    // W^T staging: WT[col][k] = att_w[k][col]  (coalesced f32 read)
    for (int idx = tid; idx < 64 * 64; idx += 256) {
        int k = idx >> 6, col = idx & 63;
        WT[col][k] = (_Float16)att_w[idx];
    }
    __syncthreads();

    // ---- phase 1: gather embeddings (f32 -> fp16 LDS), 2 samples ----
    for (int it = tid; it < 2 * F_N * 16; it += 256) {
        int ss = (it >= F_N * 16) ? 1 : 0;
        int f  = (it - ss * F_N * 16) >> 4;
        int q  = it & 15;
        const float4* src = reinterpret_cast<const float4*>(
            embed_w + ((size_t)(f * V_N + sIdx[ss][f])) * E_N);
        float4 v = src[q];
        half4 hv = {(_Float16)v.x, (_Float16)v.y, (_Float16)v.z, (_Float16)v.w};
        *reinterpret_cast<half4*>(&xwb[ss][f][q * 4]) = hv;
    }
    // W-fragments hoisted to registers ONCE (WT ready since last barrier).
    // K-slot map: (g,u) <-> k = s*32 + 8g + u, same for A and B fragments.
    half8 bfr[4][2];
    #pragma unroll
    for (int n = 0; n < 4; n++)
        #pragma unroll
        for (int s = 0; s < 2; s++)
            bfr[n][s] = *reinterpret_cast<const half8*>(
                &WT[n * 16 + c16][s * 32 + g * 8]);
    float apr[4], abr[4];
    #pragma unroll
    for (int n = 0; n < 4; n++) {
        apr[n] = att_p[n * 16 + c16];
        abr[n] = att_b[n * 16 + c16];
    }
    __syncthreads();

    // ---- phase 2: attention scores via MFMA (own sample, tiles strided 2) ----
    for (int t = wv; t < PT; t += 2) {
        int p  = t * 16 + c16;
        int pk = pijL[p];
        int ri = pk >> 8, rj = pk & 255;
        half8 af[2];
        #pragma unroll
        for (int s = 0; s < 2; s++) {
            half8 xv = *reinterpret_cast<const half8*>(&xwb[smp][ri][s * 32 + g * 8]);
            half8 yv = *reinterpret_cast<const half8*>(&xwb[smp][rj][s * 32 + g * 8]);
            af[s] = xv * yv;   // 4x v_pk_mul_f16
        }
        float scq[4] = {0.f, 0.f, 0.f, 0.f};
        #pragma unroll
        for (int n = 0; n < 4; n++) {
            floatx4 acc = (floatx4){0.f, 0.f, 0.f, 0.f};
            #pragma unroll
            for (int s = 0; s < 2; s++)
                acc = __builtin_amdgcn_mfma_f32_16x16x32_f16(af[s], bfr[n][s], acc, 0, 0, 0);
            #pragma unroll
            for (int r = 0; r < 4; r++)
                scq[r] += apr[n] * fmaxf(acc[r] + abr[n], 0.f);
        }
        // D layout: col = lane&15 (hidden n), row = (lane>>4)*4 + reg (pair)
        #pragma unroll
        for (int r = 0; r < 4; r++) {
            float sc = scq[r];
            sc += __shfl_xor(sc, 1); sc += __shfl_xor(sc, 2);
            sc += __shfl_xor(sc, 4); sc += __shfl_xor(sc, 8);
            if (c16 == 0) scoresL[smp][t * 16 + g * 4 + r] = sc;
        }
    }
    __syncthreads();

    // ---- phase 3: softmax over 325 scores, per wave-pair ----
    const int local = wv * 64 + lane;            // 0..127
    float v1 = scoresL[smp][local];
    float v2 = scoresL[smp][local + 128];
    bool  ok3 = (local + 256 < P_N);
    float v3 = ok3 ? scoresL[smp][local + 256] : -1e30f;
    float m = fmaxf(fmaxf(v1, v2), v3);
    #pragma unroll
    for (int off = 32; off; off >>= 1) m = fmaxf(m, __shfl_xor(m, off));
    if (lane == 0) wred[smp][wv] = m;
    __syncthreads();
    float M = fmaxf(wred[smp][0], wred[smp][1]);
    float e1 = __expf(v1 - M);
    float e2 = __expf(v2 - M);
    float e3 = ok3 ? __expf(v3 - M) : 0.f;
    float sm = e1 + e2 + e3;
    #pragma unroll
    for (int off = 32; off; off >>= 1) sm += __shfl_xor(sm, off);
    if (lane == 0) sred[smp][wv] = sm;
    scoresL[smp][local]       = e1;
    scoresL[smp][local + 128] = e2;
    if (ok3) scoresL[smp][local + 256] = e3;
    __syncthreads();

    // ---- phase 4: afm = sum_p w_p * (xw_i o xw_j), 8 pairs/chunk ----
    const int pp = lane >> 3;   // pair-slot within chunk
    const int el = lane & 7;    // 8-element e-chunk
    float acc[8];
    #pragma unroll
    for (int u = 0; u < 8; u++) acc[u] = 0.f;
    for (int ch = wv; ch < 42; ch += 2) {
        int p = ch * 8 + pp;
        bool valid = (p < P_N);
        int pc = valid ? p : 0;
        int pk = pijL[pc];
        int ri = pk >> 8, rj = pk & 255;
        float wp = valid ? scoresL[smp][pc] : 0.f;
        half8 xv = *reinterpret_cast<const half8*>(&xwb[smp][ri][el * 8]);
        half8 yv = *reinterpret_cast<const half8*>(&xwb[smp][rj][el * 8]);
        half8 pr = xv * yv;
        #pragma unroll
        for (int u = 0; u < 8; u++)
            acc[u] = fmaf(wp, (float)pr[u], acc[u]);
    }
    #pragma unroll
    for (int u = 0; u < 8; u++) {
        acc[u] += __shfl_xor(acc[u], 8);
        acc[u] += __shfl_xor(acc[u], 16);
        acc[u] += __shfl_xor(acc[u], 32);
    }
    if (pp == 0) {
        #pragma unroll
        for (int u = 0; u < 8; u++) afm_part[smp][wv][el * 8 + u] = acc[u];
    }
    __syncthreads();

    // ---- final: combine wave-pair partials, write afm + lr ----
    if (tid < 128) {
        int s = tid >> 6, e = tid & 63;
        float rz = 1.f / (sred[s][0] + sred[s][1]);
        float a  = (afm_part[s][0][e] + afm_part[s][1][e]) * rz;
        ws_afm[(size_t)(b0 + s) * 64 + e] = a;
    }
    if (tid < 2) {
        float lr = 0.f;
        #pragma unroll
        for (int f = 0; f < F_N; f++) lr += lrbuf[tid][f];
        ws_lr[b0 + tid] = lr;
    }
}

// ---------------- MLP head: 16 samples per block ----------------
__global__ __launch_bounds__(256, 4) void anfm_mlp_kernel(
    const float* __restrict__ ws_afm, const float* __restrict__ ws_lr,
    const float* __restrict__ w0, const float* __restrict__ b0,
    const float* __restrict__ w1, const float* __restrict__ b1,
    const float* __restrict__ w2, const float* __restrict__ b2,
    const float* __restrict__ bias, float* __restrict__ out)
{
    __shared__ float afm_t[16][64];
    __shared__ float h0t[16][256];
    const int tid  = threadIdx.x;
    const int lane = tid & 63;
    const int w    = tid >> 6;
    const int blk  = blockIdx.x;
    const int s0   = w * 4;    // this wave's first local sample

    for (int it = tid; it < 16 * 64; it += 256) {
        int s = it >> 6, e = it & 63;
        afm_t[s][e] = ws_afm[((size_t)blk * 16 + s) * 64 + e];
    }
    __syncthreads();

    // L0: 64 -> 256
    float acc0[4][4];
    float bb0[4];
    #pragma unroll
    for (int q = 0; q < 4; q++) bb0[q] = b0[lane + 64 * q];
    #pragma unroll
    for (int s = 0; s < 4; s++)
        #pragma unroll
        for (int q = 0; q < 4; q++) acc0[s][q] = bb0[q];
    for (int e = 0; e < 64; e += 4) {
        floatx4 a[4];
        #pragma unroll
        for (int s = 0; s < 4; s++)
            a[s] = *reinterpret_cast<const floatx4*>(&afm_t[s0 + s][e]);
        #pragma unroll
        for (int k = 0; k < 4; k++) {
            float wv[4];
            #pragma unroll
            for (int q = 0; q < 4; q++) wv[q] = w0[(e + k) * 256 + lane + 64 * q];
            #pragma unroll
            for (int s = 0; s < 4; s++)
                #pragma unroll
                for (int q = 0; q < 4; q++)
                    acc0[s][q] = fmaf(a[s][k], wv[q], acc0[s][q]);
        }
    }
    #pragma unroll
    for (int s = 0; s < 4; s++)
        #pragma unroll
        for (int q = 0; q < 4; q++)
            h0t[s0 + s][lane + 64 * q] = fmaxf(acc0[s][q], 0.f);
    __syncthreads();

    // L1: 256 -> 128
    float acc1[4][2];
    float bb1[2];
    #pragma unroll
    for (int q = 0; q < 2; q++) bb1[q] = b1[lane + 64 * q];
    #pragma unroll
    for (int s = 0; s < 4; s++)
        #pragma unroll
        for (int q = 0; q < 2; q++) acc1[s][q] = bb1[q];
    for (int e = 0; e < 256; e += 4) {
        floatx4 h[4];
        #pragma unroll
        for (int s = 0; s < 4; s++)
            h[s] = *reinterpret_cast<const floatx4*>(&h0t[s0 + s][e]);
        #pragma unroll
        for (int k = 0; k < 4; k++) {
            float wv[2];
            #pragma unroll
            for (int q = 0; q < 2; q++) wv[q] = w1[(e + k) * 128 + lane + 64 * q];
            #pragma unroll
            for (int s = 0; s < 4; s++)
                #pragma unroll
                for (int q = 0; q < 2; q++)
                    acc1[s][q] = fmaf(h[s][k], wv[q], acc1[s][q]);
        }
    }

    // L2: 128 -> 1, + lr + bias
    float w2a = w2[lane], w2b = w2[lane + 64];
    float base = b2[0] + bias[0];
    #pragma unroll
    for (int s = 0; s < 4; s++) {
        float part = fmaxf(acc1[s][0], 0.f) * w2a + fmaxf(acc1[s][1], 0.f) * w2b;
        #pragma unroll
        for (int off = 32; off; off >>= 1) part += __shfl_xor(part, off);
        if (lane == 0) {
            int sg = blk * 16 + s0 + s;
            out[sg] = part + base + ws_lr[sg];
        }
    }
}

extern "C" void kernel_launch(void* const* d_in, const int* in_sizes, int n_in,
                              void* d_out, int out_size, void* d_ws, size_t ws_size,
                              hipStream_t stream) {
    const int*   x_idx   = (const int*)d_in[0];
    const float* embed_w = (const float*)d_in[1];
    const float* embed_b = (const float*)d_in[2];
    const float* att_w   = (const float*)d_in[3];
    const float* att_b   = (const float*)d_in[4];
    const float* att_p   = (const float*)d_in[5];
    const float* w0      = (const float*)d_in[6];
    const float* b0      = (const float*)d_in[7];
    const float* w1      = (const float*)d_in[8];
    const float* b1      = (const float*)d_in[9];
    const float* w2      = (const float*)d_in[10];
    const float* b2      = (const float*)d_in[11];
    const float* bias    = (const float*)d_in[12];

    // ws layout: afm [B,64] f32 | lr [B] f32
    float* ws_afm = (float*)d_ws;
    float* ws_lr  = ws_afm + (size_t)B_N * E_N;
    float* out    = (float*)d_out;

    anfm_attn_kernel<<<B_N / 2, 256, 0, stream>>>(x_idx, embed_w, embed_b,
                                                  att_w, att_b, att_p,
                                                  ws_afm, ws_lr);
    anfm_mlp_kernel<<<B_N / 16, 256, 0, stream>>>(ws_afm, ws_lr,
                                                  w0, b0, w1, b1, w2, b2, bias, out);
}

// Round 6
// 48.599 us; speedup vs baseline: 1.9094x; 1.4009x over previous
//
#include <hip/hip_runtime.h>
#include <stdint.h>

// ANFM: B=4096, F=26, V=20000, E=64, P=325 pairs.
// k1: 4 samples/block, ONE WAVE PER SAMPLE. Single barrier after phase 0
//     (sIdx/lr/pij/W^T staging); then each wave is fully independent:
//     gather -> transposed MFMA attention (D = W^T @ pairs^T, so the
//     hidden-unit reduction is per-lane over regs, 2 swizzles/tile) ->
//     wave-local softmax -> weighted-pair afm -> write.
// k2: MLP head 64->256->128->1 (+lr+bias), 8 samples/block.
#define B_N 4096
#define F_N 26
#define V_N 20000
#define E_N 64
#define P_N 325
#define PT  21   // ceil(336/16) pair M-tiles (padded to 336 rows)

typedef __attribute__((ext_vector_type(8))) _Float16 half8;
typedef __attribute__((ext_vector_type(4))) _Float16 half4;
typedef __attribute__((ext_vector_type(4))) float floatx4;

// ---------------- attention kernel: 4 samples/block, 1 wave/sample --------
__global__ __launch_bounds__(256, 4) void anfm_attn_kernel(
    const int* __restrict__ x_idx, const float* __restrict__ embed_w,
    const float* __restrict__ embed_b, const float* __restrict__ att_w,
    const float* __restrict__ att_b, const float* __restrict__ att_p,
    float* __restrict__ ws_afm, float* __restrict__ ws_lr)
{
    __shared__ _Float16 xwb[4][F_N][72];   // fp16 gathered embeds (pad 72)
    __shared__ _Float16 WT[64][72];        // W^T fp16: WT[col][k] (pad 72)
    __shared__ float scoresL[4][384];
    __shared__ unsigned short pijL[336];   // (i<<8)|j per pair
    __shared__ int   sIdx[4][F_N];
    __shared__ float lrbuf[4][F_N];

    const int tid  = threadIdx.x;
    const int lane = tid & 63;
    const int wid  = tid >> 6;
    const int c16  = lane & 15;
    const int g    = lane >> 4;
    const int b    = blockIdx.x * 4 + wid;   // sample owned by this wave

    // ---- phase 0 (cooperative): indices, lr gather, pair map, W^T stage ----
    if (tid < 4 * F_N) {
        int s = tid / F_N, f = tid - s * F_N;
        int idx = x_idx[(blockIdx.x * 4 + s) * F_N + f];
        sIdx[s][f]  = idx;
        lrbuf[s][f] = embed_b[f * V_N + idx];
    }
    for (int p = tid; p < 336; p += 256) {
        int i = 0, j = 1;
        if (p < P_N) {
            i = (int)((51.0f - sqrtf(2601.0f - 8.0f * (float)p)) * 0.5f);
            if (i * (51 - i) / 2 > p) i--;
            else if ((i + 1) * (50 - i) / 2 <= p) i++;
            j = p - i * (51 - i) / 2 + i + 1;
        }
        pijL[p] = (unsigned short)((i << 8) | j);
    }
    // W^T staging: WT[col][k] = att_w[k][col]  (coalesced f32 read)
    for (int idx = tid; idx < 64 * 64; idx += 256) {
        int k = idx >> 6, col = idx & 63;
        WT[col][k] = (_Float16)att_w[idx];
    }
    // per-lane attention p / bias for hidden units n = nt*16 + g*4 + r
    float apr[16], abr[16];
    #pragma unroll
    for (int nt = 0; nt < 4; nt++)
        #pragma unroll
        for (int r = 0; r < 4; r++) {
            apr[nt * 4 + r] = att_p[nt * 16 + g * 4 + r];
            abr[nt * 4 + r] = att_b[nt * 16 + g * 4 + r];
        }
    __syncthreads();   // the ONLY block-wide barrier

    // W fragments (rows of W^T) in registers; k-slot (g,u) <-> k = s*32+8g+u
    half8 bfr[4][2];
    #pragma unroll
    for (int nt = 0; nt < 4; nt++)
        #pragma unroll
        for (int s = 0; s < 2; s++)
            bfr[nt][s] = *reinterpret_cast<const half8*>(
                &WT[nt * 16 + c16][s * 32 + g * 8]);

    // ---- phase 1 (wave-local): gather own sample's embeddings ----
    #pragma unroll
    for (int it = 0; it < 7; it++) {
        int f = it * 4 + g;
        if (f < F_N) {
            const float4* src = reinterpret_cast<const float4*>(
                embed_w + ((size_t)(f * V_N + sIdx[wid][f])) * E_N);
            float4 v = src[c16];
            half4 hv = {(_Float16)v.x, (_Float16)v.y, (_Float16)v.z, (_Float16)v.w};
            *reinterpret_cast<half4*>(&xwb[wid][f][c16 * 4]) = hv;
        }
    }

    // ---- phase 2 (wave-local): scores via TRANSPOSED MFMA ----
    // D = W^T(A) @ pairs^T(B): D col = lane&15 = pair, row = g*4+r = hidden n.
    // acc initialized with att_b -> bias comes free via the C operand.
    #pragma unroll 1
    for (int t = 0; t < PT; t++) {
        int pk = pijL[t * 16 + c16];
        int ri = pk >> 8, rj = pk & 255;
        half8 af[2];
        #pragma unroll
        for (int s = 0; s < 2; s++) {
            half8 xv = *reinterpret_cast<const half8*>(&xwb[wid][ri][s * 32 + g * 8]);
            half8 yv = *reinterpret_cast<const half8*>(&xwb[wid][rj][s * 32 + g * 8]);
            af[s] = xv * yv;   // 4x v_pk_mul_f16
        }
        float scq = 0.f;
        #pragma unroll
        for (int nt = 0; nt < 4; nt++) {
            floatx4 acc = {abr[nt * 4 + 0], abr[nt * 4 + 1],
                           abr[nt * 4 + 2], abr[nt * 4 + 3]};
            acc = __builtin_amdgcn_mfma_f32_16x16x32_f16(bfr[nt][0], af[0], acc, 0, 0, 0);
            acc = __builtin_amdgcn_mfma_f32_16x16x32_f16(bfr[nt][1], af[1], acc, 0, 0, 0);
            #pragma unroll
            for (int r = 0; r < 4; r++)
                scq = fmaf(apr[nt * 4 + r], fmaxf(acc[r], 0.f), scq);
        }
        scq += __shfl_xor(scq, 16);   // reduce over g groups (hidden chunks)
        scq += __shfl_xor(scq, 32);
        if (g == 0) scoresL[wid][t * 16 + c16] = scq;
    }

    // ---- phase 3 (wave-local): softmax over 325 scores ----
    float sv[6];
    #pragma unroll
    for (int q = 0; q < 6; q++) {
        int idx = q * 64 + lane;
        sv[q] = (idx < 336) ? scoresL[wid][idx] : -1e30f;
    }
    float m = sv[0];
    #pragma unroll
    for (int q = 1; q < 6; q++) m = fmaxf(m, sv[q]);
    #pragma unroll
    for (int off = 32; off; off >>= 1) m = fmaxf(m, __shfl_xor(m, off));
    float Z = 0.f;
    #pragma unroll
    for (int q = 0; q < 6; q++) {
        int idx = q * 64 + lane;
        float e = (idx < P_N) ? __expf(sv[q] - m) : 0.f;
        scoresL[wid][idx] = e;     // pads (>=325) get 0 -> phase 4 unguarded
        Z += e;
    }
    #pragma unroll
    for (int off = 32; off; off >>= 1) Z += __shfl_xor(Z, off);
    float rZ = 1.f / Z;

    // ---- phase 4 (wave-local): afm = sum_p w_p * (xw_i o xw_j) ----
    const int pp = lane >> 3;   // pair-slot within chunk of 8
    const int el = lane & 7;    // 8-element e-chunk
    float ac[8];
    #pragma unroll
    for (int u = 0; u < 8; u++) ac[u] = 0.f;
    #pragma unroll 6
    for (int ch = 0; ch < 42; ch++) {
        int p  = ch * 8 + pp;                 // <= 335; w_p = 0 for pads
        int pk = pijL[p];
        int ri = pk >> 8, rj = pk & 255;
        float wp = scoresL[wid][p];
        half8 xv = *reinterpret_cast<const half8*>(&xwb[wid][ri][el * 8]);
        half8 yv = *reinterpret_cast<const half8*>(&xwb[wid][rj][el * 8]);
        half8 pr = xv * yv;
        #pragma unroll
        for (int u = 0; u < 8; u++)
            ac[u] = fmaf(wp, (float)pr[u], ac[u]);
    }
    #pragma unroll
    for (int u = 0; u < 8; u++) {
        ac[u] += __shfl_xor(ac[u], 8);
        ac[u] += __shfl_xor(ac[u], 16);
        ac[u] += __shfl_xor(ac[u], 32);
    }
    if (lane < 8) {
        floatx4 o0 = {ac[0] * rZ, ac[1] * rZ, ac[2] * rZ, ac[3] * rZ};
        floatx4 o1 = {ac[4] * rZ, ac[5] * rZ, ac[6] * rZ, ac[7] * rZ};
        *reinterpret_cast<floatx4*>(&ws_afm[(size_t)b * 64 + lane * 8])     = o0;
        *reinterpret_cast<floatx4*>(&ws_afm[(size_t)b * 64 + lane * 8 + 4]) = o1;
    }
    float lv = (lane < F_N) ? lrbuf[wid][lane] : 0.f;
    #pragma unroll
    for (int off = 32; off; off >>= 1) lv += __shfl_xor(lv, off);
    if (lane == 0) ws_lr[b] = lv;
}

// ---------------- MLP head: 8 samples per block ----------------
__global__ __launch_bounds__(256, 4) void anfm_mlp_kernel(
    const float* __restrict__ ws_afm, const float* __restrict__ ws_lr,
    const float* __restrict__ w0, const float* __restrict__ b0,
    const float* __restrict__ w1, const float* __restrict__ b1,
    const float* __restrict__ w2, const float* __restrict__ b2,
    const float* __restrict__ bias, float* __restrict__ out)
{
    __shared__ float afm_t[8][64];
    __shared__ float h0t[8][256];
    const int tid  = threadIdx.x;
    const int lane = tid & 63;
    const int w    = tid >> 6;
    const int blk  = blockIdx.x;
    const int s0   = w * 2;    // this wave's first local sample

    for (int it = tid; it < 8 * 64; it += 256) {
        int s = it >> 6, e = it & 63;
        afm_t[s][e] = ws_afm[((size_t)blk * 8 + s) * 64 + e];
    }
    __syncthreads();

    // L0: 64 -> 256
    float acc0[2][4];
    float bb0[4];
    #pragma unroll
    for (int q = 0; q < 4; q++) bb0[q] = b0[lane + 64 * q];
    #pragma unroll
    for (int s = 0; s < 2; s++)
        #pragma unroll
        for (int q = 0; q < 4; q++) acc0[s][q] = bb0[q];
    for (int e = 0; e < 64; e += 4) {
        floatx4 a[2];
        #pragma unroll
        for (int s = 0; s < 2; s++)
            a[s] = *reinterpret_cast<const floatx4*>(&afm_t[s0 + s][e]);
        #pragma unroll
        for (int k = 0; k < 4; k++) {
            float wv[4];
            #pragma unroll
            for (int q = 0; q < 4; q++) wv[q] = w0[(e + k) * 256 + lane + 64 * q];
            #pragma unroll
            for (int s = 0; s < 2; s++)
                #pragma unroll
                for (int q = 0; q < 4; q++)
                    acc0[s][q] = fmaf(a[s][k], wv[q], acc0[s][q]);
        }
    }
    #pragma unroll
    for (int s = 0; s < 2; s++)
        #pragma unroll
        for (int q = 0; q < 4; q++)
            h0t[s0 + s][lane + 64 * q] = fmaxf(acc0[s][q], 0.f);
    __syncthreads();

    // L1: 256 -> 128
    float acc1[2][2];
    float bb1[2];
    #pragma unroll
    for (int q = 0; q < 2; q++) bb1[q] = b1[lane + 64 * q];
    #pragma unroll
    for (int s = 0; s < 2; s++)
        #pragma unroll
        for (int q = 0; q < 2; q++) acc1[s][q] = bb1[q];
    for (int e = 0; e < 256; e += 4) {
        floatx4 h[2];
        #pragma unroll
        for (int s = 0; s < 2; s++)
            h[s] = *reinterpret_cast<const floatx4*>(&h0t[s0 + s][e]);
        #pragma unroll
        for (int k = 0; k < 4; k++) {
            float wv[2];
            #pragma unroll
            for (int q = 0; q < 2; q++) wv[q] = w1[(e + k) * 128 + lane + 64 * q];
            #pragma unroll
            for (int s = 0; s < 2; s++)
                #pragma unroll
                for (int q = 0; q < 2; q++)
                    acc1[s][q] = fmaf(h[s][k], wv[q], acc1[s][q]);
        }
    }

    // L2: 128 -> 1, + lr + bias
    float w2a = w2[lane], w2b = w2[lane + 64];
    float base = b2[0] + bias[0];
    #pragma unroll
    for (int s = 0; s < 2; s++) {
        float part = fmaxf(acc1[s][0], 0.f) * w2a + fmaxf(acc1[s][1], 0.f) * w2b;
        #pragma unroll
        for (int off = 32; off; off >>= 1) part += __shfl_xor(part, off);
        if (lane == 0) {
            int sg = blk * 8 + s0 + s;
            out[sg] = part + base + ws_lr[sg];
        }
    }
}

extern "C" void kernel_launch(void* const* d_in, const int* in_sizes, int n_in,
                              void* d_out, int out_size, void* d_ws, size_t ws_size,
                              hipStream_t stream) {
    const int*   x_idx   = (const int*)d_in[0];
    const float* embed_w = (const float*)d_in[1];
    const float* embed_b = (const float*)d_in[2];
    const float* att_w   = (const float*)d_in[3];
    const float* att_b   = (const float*)d_in[4];
    const float* att_p   = (const float*)d_in[5];
    const float* w0      = (const float*)d_in[6];
    const float* b0      = (const float*)d_in[7];
    const float* w1      = (const float*)d_in[8];
    const float* b1      = (const float*)d_in[9];
    const float* w2      = (const float*)d_in[10];
    const float* b2      = (const float*)d_in[11];
    const float* bias    = (const float*)d_in[12];

    // ws layout: afm [B,64] f32 | lr [B] f32
    float* ws_afm = (float*)d_ws;
    float* ws_lr  = ws_afm + (size_t)B_N * E_N;
    float* out    = (float*)d_out;

    anfm_attn_kernel<<<B_N / 4, 256, 0, stream>>>(x_idx, embed_w, embed_b,
                                                  att_w, att_b, att_p,
                                                  ws_afm, ws_lr);
    anfm_mlp_kernel<<<B_N / 8, 256, 0, stream>>>(ws_afm, ws_lr,
                                                 w0, b0, w1, b1, w2, b2, bias, out);
}